// Round 1
// baseline (333.873 us; speedup 1.0000x reference)
//
#include <hip/hip_runtime.h>

#define D 64
#define K3 192  // 3*D
#define OUTD 64

// ---------------------------------------------------------------------------
// Pass 1: per-dst segment max of w (pos edges) and |w| (neg edges).
// All contributing values are > 0, so uint-bit atomicMax == float max,
// with init 0.0f (empty-segment max is never consumed downstream).
// ---------------------------------------------------------------------------
__global__ void edge_max_kernel(const float* __restrict__ w,
                                const int* __restrict__ dst,
                                unsigned int* __restrict__ m_pos,
                                unsigned int* __restrict__ m_neg,
                                int E) {
    int i = blockIdx.x * blockDim.x + threadIdx.x;
    if (i >= E) return;
    float we = w[i];
    if (we > 0.0f) {
        atomicMax(&m_pos[dst[i]], __float_as_uint(we));
    } else if (we < 0.0f) {
        atomicMax(&m_neg[dst[i]], __float_as_uint(-we));
    }
}

// ---------------------------------------------------------------------------
// Pass 2: per-dst segment sum of exp(l - m[dst]).
// ---------------------------------------------------------------------------
__global__ void edge_sum_kernel(const float* __restrict__ w,
                                const int* __restrict__ dst,
                                const float* __restrict__ m_pos,
                                const float* __restrict__ m_neg,
                                float* __restrict__ s_pos,
                                float* __restrict__ s_neg,
                                int E) {
    int i = blockIdx.x * blockDim.x + threadIdx.x;
    if (i >= E) return;
    float we = w[i];
    if (we == 0.0f) return;
    int d = dst[i];
    bool pos = we > 0.0f;
    float l = fabsf(we);
    float m = pos ? m_pos[d] : m_neg[d];
    float e = __expf(l - m);
    atomicAdd(pos ? &s_pos[d] : &s_neg[d], e);
}

// ---------------------------------------------------------------------------
// Pass 3: edge aggregation. One wave (64 lanes) per edge; lane = feature dim.
// a = exp(l - m[dst]) / (s[dst] + 1e-16); h[dst] += feat[src] * a.
// Gather and atomic scatter are both coalesced 256B per wave.
// ---------------------------------------------------------------------------
__global__ void edge_agg_kernel(const float* __restrict__ w,
                                const int* __restrict__ src,
                                const int* __restrict__ dst,
                                const float* __restrict__ feat,
                                const float* __restrict__ m_pos,
                                const float* __restrict__ m_neg,
                                const float* __restrict__ s_pos,
                                const float* __restrict__ s_neg,
                                float* __restrict__ h_pos,
                                float* __restrict__ h_neg,
                                int E) {
    int lane = threadIdx.x & 63;
    int wid = (blockIdx.x * blockDim.x + threadIdx.x) >> 6;
    int nw = (gridDim.x * blockDim.x) >> 6;
    for (int e = wid; e < E; e += nw) {
        float we = w[e];
        if (we == 0.0f) continue;
        int d = dst[e];
        int s = src[e];
        bool pos = we > 0.0f;
        float l = fabsf(we);
        float m = pos ? m_pos[d] : m_neg[d];
        float ssum = pos ? s_pos[d] : s_neg[d];
        float a = __expf(l - m) / (ssum + 1e-16f);
        float v = feat[(size_t)s * D + lane] * a;
        float* h = pos ? h_pos : h_neg;
        atomicAdd(&h[(size_t)d * D + lane], v);
    }
}

// ---------------------------------------------------------------------------
// Pass 4: output projection. out[n][o] = sum_k comb[n][k] * W_fc[o][k] + b.
// Thread-per-node; W_fc staged TRANSPOSED in LDS (Wt[k][o]) so the inner
// reads are wave-uniform broadcasts (no bank conflicts). 64 f32 acc/thread.
// ---------------------------------------------------------------------------
__global__ __launch_bounds__(256) void out_gemm_kernel(
        const float* __restrict__ feat,
        const float* __restrict__ h_pos,
        const float* __restrict__ h_neg,
        const float* __restrict__ W_fc,
        const float* __restrict__ b_fc,
        const float* __restrict__ bias,
        const float* __restrict__ coef_self,
        const float* __restrict__ coef_posi,
        const float* __restrict__ coef_nega,
        float* __restrict__ out,
        int N) {
    __shared__ float Wt[K3 * OUTD];  // Wt[k][o] = W_fc[o][k]
    for (int i = threadIdx.x; i < K3 * OUTD; i += blockDim.x) {
        int k = i >> 6;
        int o = i & 63;
        Wt[i] = W_fc[o * K3 + k];
    }
    __syncthreads();

    int n = blockIdx.x * blockDim.x + threadIdx.x;
    if (n >= N) return;

    float cf[3];
    cf[0] = coef_self[0];
    cf[1] = coef_posi[0];
    cf[2] = coef_nega[0];
    const float* segs[3];
    segs[0] = feat;
    segs[1] = h_pos;
    segs[2] = h_neg;

    float acc[OUTD];
#pragma unroll
    for (int o = 0; o < OUTD; ++o) acc[o] = b_fc[o] + bias[o];

    for (int sg = 0; sg < 3; ++sg) {
        const float4* p = (const float4*)(segs[sg] + (size_t)n * D);
        float c = cf[sg];
        for (int kk = 0; kk < D / 4; ++kk) {
            float4 v4 = p[kk];
            float cv[4];
            cv[0] = v4.x * c; cv[1] = v4.y * c; cv[2] = v4.z * c; cv[3] = v4.w * c;
#pragma unroll
            for (int j = 0; j < 4; ++j) {
                const float* wrow = &Wt[((sg * (D / 4) + kk) * 4 + j) * OUTD];
#pragma unroll
                for (int o = 0; o < OUTD; o += 4) {
                    float4 wv = *(const float4*)&wrow[o];
                    acc[o + 0] += cv[j] * wv.x;
                    acc[o + 1] += cv[j] * wv.y;
                    acc[o + 2] += cv[j] * wv.z;
                    acc[o + 3] += cv[j] * wv.w;
                }
            }
        }
    }

    float* op = out + (size_t)n * OUTD;
#pragma unroll
    for (int o = 0; o < OUTD; o += 4) {
        float4 r;
        r.x = acc[o + 0]; r.y = acc[o + 1]; r.z = acc[o + 2]; r.w = acc[o + 3];
        *(float4*)&op[o] = r;
    }
}

extern "C" void kernel_launch(void* const* d_in, const int* in_sizes, int n_in,
                              void* d_out, int out_size, void* d_ws, size_t ws_size,
                              hipStream_t stream) {
    const float* feat      = (const float*)d_in[0];
    const float* w         = (const float*)d_in[1];
    const float* W_fc      = (const float*)d_in[2];
    const float* b_fc      = (const float*)d_in[3];
    const float* bias      = (const float*)d_in[4];
    const float* coef_self = (const float*)d_in[5];
    const float* coef_posi = (const float*)d_in[6];
    const float* coef_nega = (const float*)d_in[7];
    const int*   src       = (const int*)d_in[8];
    const int*   dst       = (const int*)d_in[9];

    const int E = in_sizes[1];
    const int N = in_sizes[0] / D;

    // Workspace layout (floats): m_pos[N] m_neg[N] s_pos[N] s_neg[N] h_pos[N*D] h_neg[N*D]
    float* ws    = (float*)d_ws;
    float* m_pos = ws;
    float* m_neg = ws + (size_t)N;
    float* s_pos = ws + (size_t)2 * N;
    float* s_neg = ws + (size_t)3 * N;
    float* h_pos = ws + (size_t)4 * N;
    float* h_neg = ws + (size_t)4 * N + (size_t)N * D;
    size_t ws_used_bytes = ((size_t)4 * N + (size_t)2 * N * D) * sizeof(float);

    // Zero-init scratch every call (ws is poisoned once, never re-poisoned).
    hipMemsetAsync(d_ws, 0, ws_used_bytes, stream);

    int eb = (E + 255) / 256;
    edge_max_kernel<<<eb, 256, 0, stream>>>(w, dst, (unsigned int*)m_pos,
                                            (unsigned int*)m_neg, E);
    edge_sum_kernel<<<eb, 256, 0, stream>>>(w, dst, m_pos, m_neg, s_pos, s_neg, E);

    edge_agg_kernel<<<2048, 256, 0, stream>>>(w, src, dst, feat, m_pos, m_neg,
                                              s_pos, s_neg, h_pos, h_neg, E);

    int nb = (N + 255) / 256;
    out_gemm_kernel<<<nb, 256, 0, stream>>>(feat, h_pos, h_neg, W_fc, b_fc, bias,
                                            coef_self, coef_posi, coef_nega,
                                            (float*)d_out, N);
}

// Round 2
// 332.931 us; speedup vs baseline: 1.0028x; 1.0028x over previous
//
#include <hip/hip_runtime.h>

#define D 64
#define K3 192  // 3*D
#define OUTD 64

// ---------------------------------------------------------------------------
// Pass 1: histogram of dst -> counts[N]
// ---------------------------------------------------------------------------
__global__ void hist_kernel(const int* __restrict__ dst,
                            int* __restrict__ counts, int E) {
    int i = blockIdx.x * blockDim.x + threadIdx.x;
    if (i < E) atomicAdd(&counts[dst[i]], 1);
}

// ---------------------------------------------------------------------------
// Pass 2: single-block exclusive scan of counts[N] -> offs (in place) and
// cursor copy. offs[N] = total. 1024 threads, ~49 elements each.
// ---------------------------------------------------------------------------
__global__ __launch_bounds__(1024) void scan_kernel(int* __restrict__ counts, // len N+1; becomes offs
                                                    int* __restrict__ cursor, // len N
                                                    int N) {
    __shared__ int part[1024];
    int t = threadIdx.x;
    int per = (N + 1023) / 1024;
    int start = t * per;
    int end = min(start + per, N);
    int s = 0;
    for (int i = start; i < end; ++i) s += counts[i];
    part[t] = s;
    __syncthreads();
    // Hillis-Steele inclusive scan over 1024 partials
    for (int off = 1; off < 1024; off <<= 1) {
        int v = (t >= off) ? part[t - off] : 0;
        __syncthreads();
        part[t] += v;
        __syncthreads();
    }
    int running = (t == 0) ? 0 : part[t - 1];  // exclusive prefix
    for (int i = start; i < end; ++i) {
        int c = counts[i];
        counts[i] = running;
        cursor[i] = running;
        running += c;
    }
    if (t == 1023) counts[N] = part[1023];  // total = E
}

// ---------------------------------------------------------------------------
// Pass 3: scatter edges into dst-sorted order (payload: src, w).
// ---------------------------------------------------------------------------
__global__ void scatter_kernel(const float* __restrict__ w,
                               const int* __restrict__ src,
                               const int* __restrict__ dst,
                               int* __restrict__ cursor,
                               int* __restrict__ e_src,
                               float* __restrict__ e_w, int E) {
    int i = blockIdx.x * blockDim.x + threadIdx.x;
    if (i >= E) return;
    int d = dst[i];
    int p = atomicAdd(&cursor[d], 1);
    e_src[p] = src[i];
    e_w[p] = w[i];
}

// ---------------------------------------------------------------------------
// Pass 4: fused per-node softmax (pos & neg) + aggregation. One wave/node.
// Phase A: lane-parallel over edges -> shuffle-reduce max.
// Phase B: lane-parallel exp -> shuffle-reduce sums.
// Phase C: serial over edges, lane = feature dim; coalesced 256B gathers,
//          streaming 512B store per node. No atomics.
// ---------------------------------------------------------------------------
__global__ __launch_bounds__(256) void node_agg_kernel(
        const float* __restrict__ feat,
        const int* __restrict__ offs,     // len N+1
        const int* __restrict__ e_src,
        const float* __restrict__ e_w,
        float* __restrict__ h_pos,
        float* __restrict__ h_neg, int N) {
    int lane = threadIdx.x & 63;
    int node = (blockIdx.x * blockDim.x + threadIdx.x) >> 6;
    if (node >= N) return;
    int beg = offs[node];
    int end = offs[node + 1];

    // Phase A: masked maxes
    float mp = -1e30f, mn = -1e30f;
    for (int base = beg; base < end; base += 64) {
        int e = base + lane;
        float we = (e < end) ? e_w[e] : 0.0f;
        if (we > 0.0f) mp = fmaxf(mp, we);
        else if (we < 0.0f) mn = fmaxf(mn, -we);
    }
#pragma unroll
    for (int o = 32; o >= 1; o >>= 1) {
        mp = fmaxf(mp, __shfl_xor(mp, o));
        mn = fmaxf(mn, __shfl_xor(mn, o));
    }

    // Phase B: denominators
    float sp = 0.0f, sn = 0.0f;
    for (int base = beg; base < end; base += 64) {
        int e = base + lane;
        float we = (e < end) ? e_w[e] : 0.0f;
        if (we > 0.0f) sp += __expf(we - mp);
        else if (we < 0.0f) sn += __expf(-we - mn);
    }
#pragma unroll
    for (int o = 32; o >= 1; o >>= 1) {
        sp += __shfl_xor(sp, o);
        sn += __shfl_xor(sn, o);
    }
    float rp = 1.0f / (sp + 1e-16f);
    float rn = 1.0f / (sn + 1e-16f);

    // Phase C: aggregation
    float accp = 0.0f, accn = 0.0f;
    for (int base = beg; base < end; base += 64) {
        int e = base + lane;
        bool valid = e < end;
        float we = valid ? e_w[e] : 0.0f;
        int se = valid ? e_src[e] : 0;
        float a;
        if (we > 0.0f) a = __expf(we - mp) * rp;
        else if (we < 0.0f) a = __expf(-we - mn) * rn;
        else a = 0.0f;
        int cnt = min(64, end - base);
        for (int j = 0; j < cnt; ++j) {
            float wj = __shfl(we, j);
            if (wj == 0.0f) continue;
            float aj = __shfl(a, j);
            int sj = __shfl(se, j);
            float v = feat[(size_t)sj * D + lane] * aj;
            if (wj > 0.0f) accp += v;
            else accn += v;
        }
    }
    h_pos[(size_t)node * D + lane] = accp;
    h_neg[(size_t)node * D + lane] = accn;
}

// ---------------------------------------------------------------------------
// Pass 5: output projection. out[n][o] = sum_k comb[n][k] * W_fc[o][k] + b.
// Thread-per-node; W_fc staged transposed in LDS (broadcast reads).
// ---------------------------------------------------------------------------
__global__ __launch_bounds__(256) void out_gemm_kernel(
        const float* __restrict__ feat,
        const float* __restrict__ h_pos,
        const float* __restrict__ h_neg,
        const float* __restrict__ W_fc,
        const float* __restrict__ b_fc,
        const float* __restrict__ bias,
        const float* __restrict__ coef_self,
        const float* __restrict__ coef_posi,
        const float* __restrict__ coef_nega,
        float* __restrict__ out,
        int N) {
    __shared__ float Wt[K3 * OUTD];  // Wt[k][o] = W_fc[o][k]
    for (int i = threadIdx.x; i < K3 * OUTD; i += blockDim.x) {
        int k = i >> 6;
        int o = i & 63;
        Wt[i] = W_fc[o * K3 + k];
    }
    __syncthreads();

    int n = blockIdx.x * blockDim.x + threadIdx.x;
    if (n >= N) return;

    float cf[3];
    cf[0] = coef_self[0];
    cf[1] = coef_posi[0];
    cf[2] = coef_nega[0];
    const float* segs[3];
    segs[0] = feat;
    segs[1] = h_pos;
    segs[2] = h_neg;

    float acc[OUTD];
#pragma unroll
    for (int o = 0; o < OUTD; ++o) acc[o] = b_fc[o] + bias[o];

    for (int sg = 0; sg < 3; ++sg) {
        const float4* p = (const float4*)(segs[sg] + (size_t)n * D);
        float c = cf[sg];
        for (int kk = 0; kk < D / 4; ++kk) {
            float4 v4 = p[kk];
            float cv[4];
            cv[0] = v4.x * c; cv[1] = v4.y * c; cv[2] = v4.z * c; cv[3] = v4.w * c;
#pragma unroll
            for (int j = 0; j < 4; ++j) {
                const float* wrow = &Wt[((sg * (D / 4) + kk) * 4 + j) * OUTD];
#pragma unroll
                for (int o = 0; o < OUTD; o += 4) {
                    float4 wv = *(const float4*)&wrow[o];
                    acc[o + 0] += cv[j] * wv.x;
                    acc[o + 1] += cv[j] * wv.y;
                    acc[o + 2] += cv[j] * wv.z;
                    acc[o + 3] += cv[j] * wv.w;
                }
            }
        }
    }

    float* op = out + (size_t)n * OUTD;
#pragma unroll
    for (int o = 0; o < OUTD; o += 4) {
        float4 r;
        r.x = acc[o + 0]; r.y = acc[o + 1]; r.z = acc[o + 2]; r.w = acc[o + 3];
        *(float4*)&op[o] = r;
    }
}

extern "C" void kernel_launch(void* const* d_in, const int* in_sizes, int n_in,
                              void* d_out, int out_size, void* d_ws, size_t ws_size,
                              hipStream_t stream) {
    const float* feat      = (const float*)d_in[0];
    const float* w         = (const float*)d_in[1];
    const float* W_fc      = (const float*)d_in[2];
    const float* b_fc      = (const float*)d_in[3];
    const float* bias      = (const float*)d_in[4];
    const float* coef_self = (const float*)d_in[5];
    const float* coef_posi = (const float*)d_in[6];
    const float* coef_nega = (const float*)d_in[7];
    const int*   src       = (const int*)d_in[8];
    const int*   dst       = (const int*)d_in[9];

    const int E = in_sizes[1];
    const int N = in_sizes[0] / D;

    // Workspace layout (4B elems):
    //   counts/offs [N+1] | cursor [N] | e_src [E] | e_w [E] | h_pos [N*D] | h_neg [N*D]
    char* ws = (char*)d_ws;
    int*   counts = (int*)ws;                                 // becomes offs
    int*   cursor = (int*)(ws + (size_t)(N + 1) * 4);
    int*   e_src  = (int*)(ws + (size_t)(2 * N + 1) * 4);
    float* e_w    = (float*)(ws + (size_t)(2 * N + 1 + E) * 4);
    float* h_pos  = (float*)(ws + (size_t)(2 * N + 1 + 2 * E) * 4);
    float* h_neg  = h_pos + (size_t)N * D;

    // Zero only the histogram (h arrays are fully written each call).
    hipMemsetAsync(counts, 0, (size_t)N * 4, stream);

    int eb = (E + 255) / 256;
    hist_kernel<<<eb, 256, 0, stream>>>(dst, counts, E);
    scan_kernel<<<1, 1024, 0, stream>>>(counts, cursor, N);
    scatter_kernel<<<eb, 256, 0, stream>>>(w, src, dst, cursor, e_src, e_w, E);

    int nb = (N * 64 + 255) / 256;
    node_agg_kernel<<<nb, 256, 0, stream>>>(feat, counts, e_src, e_w,
                                            h_pos, h_neg, N);

    int gb = (N + 255) / 256;
    out_gemm_kernel<<<gb, 256, 0, stream>>>(feat, h_pos, h_neg, W_fc, b_fc, bias,
                                            coef_self, coef_posi, coef_nega,
                                            (float*)d_out, N);
}

// Round 3
// 241.778 us; speedup vs baseline: 1.3809x; 1.3770x over previous
//
#include <hip/hip_runtime.h>

#define D 64
#define K3 192  // 3*D
#define OUTD 64
#define CHUNK 1024  // elements per scan block (256 thr x 4)

// ---------------------------------------------------------------------------
// Pass 1: histogram of dst -> counts[N]
// ---------------------------------------------------------------------------
__global__ void hist_kernel(const int* __restrict__ dst,
                            int* __restrict__ counts, int E) {
    int i = blockIdx.x * blockDim.x + threadIdx.x;
    if (i < E) atomicAdd(&counts[dst[i]], 1);
}

// ---------------------------------------------------------------------------
// Pass 2a: per-chunk reduce -> chunksum[nchunks]
// ---------------------------------------------------------------------------
__global__ __launch_bounds__(256) void scan_chunk_reduce(
        const int* __restrict__ counts, int* __restrict__ chunksum, int N) {
    int base = blockIdx.x * CHUNK;
    int t = threadIdx.x;
    int idx = base + t * 4;
    int s = 0;
    if (idx + 3 < N) {
        int4 v = *(const int4*)&counts[idx];
        s = v.x + v.y + v.z + v.w;
    } else {
        for (int j = 0; j < 4; ++j)
            if (idx + j < N) s += counts[idx + j];
    }
#pragma unroll
    for (int o = 32; o >= 1; o >>= 1) s += __shfl_xor(s, o);
    __shared__ int wt[4];
    if ((t & 63) == 0) wt[t >> 6] = s;
    __syncthreads();
    if (t == 0) chunksum[blockIdx.x] = wt[0] + wt[1] + wt[2] + wt[3];
}

// ---------------------------------------------------------------------------
// Pass 2b: single-block exclusive scan of chunksums (nchunks <= 256).
// Also writes offs[N] = total (= E).
// ---------------------------------------------------------------------------
__global__ __launch_bounds__(256) void scan_chunksums(
        int* __restrict__ chunksum, int nchunks, int* __restrict__ offsN) {
    __shared__ int sh[256];
    int t = threadIdx.x;
    int v = (t < nchunks) ? chunksum[t] : 0;
    sh[t] = v;
    __syncthreads();
    for (int o = 1; o < 256; o <<= 1) {
        int u = (t >= o) ? sh[t - o] : 0;
        __syncthreads();
        sh[t] += u;
        __syncthreads();
    }
    if (t < nchunks) chunksum[t] = sh[t] - v;   // exclusive
    if (t == nchunks - 1) *offsN = sh[t];       // total = E
}

// ---------------------------------------------------------------------------
// Pass 2c: per-chunk apply: block-local scan + chunk base -> offs, cursor.
// In-place over counts (each thread reads its own 4 before writing them).
// ---------------------------------------------------------------------------
__global__ __launch_bounds__(256) void scan_chunk_apply(
        int* __restrict__ counts,             // in: counts, out: offs
        const int* __restrict__ chunkbase,    // exclusive chunk prefixes
        int* __restrict__ cursor, int N) {
    int base = blockIdx.x * CHUNK;
    int t = threadIdx.x;
    int lane = t & 63;
    int wid = t >> 6;
    int idx = base + t * 4;
    int v[4] = {0, 0, 0, 0};
    if (idx + 3 < N) {
        int4 x = *(const int4*)&counts[idx];
        v[0] = x.x; v[1] = x.y; v[2] = x.z; v[3] = x.w;
    } else {
        for (int j = 0; j < 4; ++j)
            if (idx + j < N) v[j] = counts[idx + j];
    }
    int s = v[0] + v[1] + v[2] + v[3];
    int incl = s;
#pragma unroll
    for (int o = 1; o < 64; o <<= 1) {
        int u = __shfl_up(incl, o);
        if (lane >= o) incl += u;
    }
    __shared__ int wt[4];
    if (lane == 63) wt[wid] = incl;
    __syncthreads();
    int wbase = 0;
    for (int j = 0; j < wid; ++j) wbase += wt[j];
    int run = chunkbase[blockIdx.x] + wbase + (incl - s);
    for (int j = 0; j < 4; ++j) {
        int ij = idx + j;
        if (ij < N) {
            counts[ij] = run;
            cursor[ij] = run;
            run += v[j];
        }
    }
}

// ---------------------------------------------------------------------------
// Pass 3: scatter edges into dst-sorted order (payload: src, w).
// ---------------------------------------------------------------------------
__global__ void scatter_kernel(const float* __restrict__ w,
                               const int* __restrict__ src,
                               const int* __restrict__ dst,
                               int* __restrict__ cursor,
                               int* __restrict__ e_src,
                               float* __restrict__ e_w, int E) {
    int i = blockIdx.x * blockDim.x + threadIdx.x;
    if (i >= E) return;
    int d = dst[i];
    int p = atomicAdd(&cursor[d], 1);
    e_src[p] = src[i];
    e_w[p] = w[i];
}

// ---------------------------------------------------------------------------
// Pass 4: fused per-node softmax (pos & neg) + aggregation. One wave/node.
// ---------------------------------------------------------------------------
__global__ __launch_bounds__(256) void node_agg_kernel(
        const float* __restrict__ feat,
        const int* __restrict__ offs,     // len N+1
        const int* __restrict__ e_src,
        const float* __restrict__ e_w,
        float* __restrict__ h_pos,
        float* __restrict__ h_neg, int N) {
    int lane = threadIdx.x & 63;
    int node = (blockIdx.x * blockDim.x + threadIdx.x) >> 6;
    if (node >= N) return;
    int beg = offs[node];
    int end = offs[node + 1];

    // Phase A: masked maxes
    float mp = -1e30f, mn = -1e30f;
    for (int base = beg; base < end; base += 64) {
        int e = base + lane;
        float we = (e < end) ? e_w[e] : 0.0f;
        if (we > 0.0f) mp = fmaxf(mp, we);
        else if (we < 0.0f) mn = fmaxf(mn, -we);
    }
#pragma unroll
    for (int o = 32; o >= 1; o >>= 1) {
        mp = fmaxf(mp, __shfl_xor(mp, o));
        mn = fmaxf(mn, __shfl_xor(mn, o));
    }

    // Phase B: denominators
    float sp = 0.0f, sn = 0.0f;
    for (int base = beg; base < end; base += 64) {
        int e = base + lane;
        float we = (e < end) ? e_w[e] : 0.0f;
        if (we > 0.0f) sp += __expf(we - mp);
        else if (we < 0.0f) sn += __expf(-we - mn);
    }
#pragma unroll
    for (int o = 32; o >= 1; o >>= 1) {
        sp += __shfl_xor(sp, o);
        sn += __shfl_xor(sn, o);
    }
    float rp = 1.0f / (sp + 1e-16f);
    float rn = 1.0f / (sn + 1e-16f);

    // Phase C: aggregation
    float accp = 0.0f, accn = 0.0f;
    for (int base = beg; base < end; base += 64) {
        int e = base + lane;
        bool valid = e < end;
        float we = valid ? e_w[e] : 0.0f;
        int se = valid ? e_src[e] : 0;
        float a;
        if (we > 0.0f) a = __expf(we - mp) * rp;
        else if (we < 0.0f) a = __expf(-we - mn) * rn;
        else a = 0.0f;
        int cnt = min(64, end - base);
        for (int j = 0; j < cnt; ++j) {
            float wj = __shfl(we, j);
            if (wj == 0.0f) continue;
            float aj = __shfl(a, j);
            int sj = __shfl(se, j);
            float v = feat[(size_t)sj * D + lane] * aj;
            if (wj > 0.0f) accp += v;
            else accn += v;
        }
    }
    h_pos[(size_t)node * D + lane] = accp;
    h_neg[(size_t)node * D + lane] = accn;
}

// ---------------------------------------------------------------------------
// Pass 5: output projection.
// ---------------------------------------------------------------------------
__global__ __launch_bounds__(256) void out_gemm_kernel(
        const float* __restrict__ feat,
        const float* __restrict__ h_pos,
        const float* __restrict__ h_neg,
        const float* __restrict__ W_fc,
        const float* __restrict__ b_fc,
        const float* __restrict__ bias,
        const float* __restrict__ coef_self,
        const float* __restrict__ coef_posi,
        const float* __restrict__ coef_nega,
        float* __restrict__ out,
        int N) {
    __shared__ float Wt[K3 * OUTD];  // Wt[k][o] = W_fc[o][k]
    for (int i = threadIdx.x; i < K3 * OUTD; i += blockDim.x) {
        int k = i >> 6;
        int o = i & 63;
        Wt[i] = W_fc[o * K3 + k];
    }
    __syncthreads();

    int n = blockIdx.x * blockDim.x + threadIdx.x;
    if (n >= N) return;

    float cf[3];
    cf[0] = coef_self[0];
    cf[1] = coef_posi[0];
    cf[2] = coef_nega[0];
    const float* segs[3];
    segs[0] = feat;
    segs[1] = h_pos;
    segs[2] = h_neg;

    float acc[OUTD];
#pragma unroll
    for (int o = 0; o < OUTD; ++o) acc[o] = b_fc[o] + bias[o];

    for (int sg = 0; sg < 3; ++sg) {
        const float4* p = (const float4*)(segs[sg] + (size_t)n * D);
        float c = cf[sg];
        for (int kk = 0; kk < D / 4; ++kk) {
            float4 v4 = p[kk];
            float cv[4];
            cv[0] = v4.x * c; cv[1] = v4.y * c; cv[2] = v4.z * c; cv[3] = v4.w * c;
#pragma unroll
            for (int j = 0; j < 4; ++j) {
                const float* wrow = &Wt[((sg * (D / 4) + kk) * 4 + j) * OUTD];
#pragma unroll
                for (int o = 0; o < OUTD; o += 4) {
                    float4 wv = *(const float4*)&wrow[o];
                    acc[o + 0] += cv[j] * wv.x;
                    acc[o + 1] += cv[j] * wv.y;
                    acc[o + 2] += cv[j] * wv.z;
                    acc[o + 3] += cv[j] * wv.w;
                }
            }
        }
    }

    float* op = out + (size_t)n * OUTD;
#pragma unroll
    for (int o = 0; o < OUTD; o += 4) {
        float4 r;
        r.x = acc[o + 0]; r.y = acc[o + 1]; r.z = acc[o + 2]; r.w = acc[o + 3];
        *(float4*)&op[o] = r;
    }
}

extern "C" void kernel_launch(void* const* d_in, const int* in_sizes, int n_in,
                              void* d_out, int out_size, void* d_ws, size_t ws_size,
                              hipStream_t stream) {
    const float* feat      = (const float*)d_in[0];
    const float* w         = (const float*)d_in[1];
    const float* W_fc      = (const float*)d_in[2];
    const float* b_fc      = (const float*)d_in[3];
    const float* bias      = (const float*)d_in[4];
    const float* coef_self = (const float*)d_in[5];
    const float* coef_posi = (const float*)d_in[6];
    const float* coef_nega = (const float*)d_in[7];
    const int*   src       = (const int*)d_in[8];
    const int*   dst       = (const int*)d_in[9];

    const int E = in_sizes[1];
    const int N = in_sizes[0] / D;
    const int nchunks = (N + CHUNK - 1) / CHUNK;  // 49 for N=50000 (<=256 req.)

    // Workspace layout (4B elems):
    //   counts/offs [N+1] | cursor [N] | chunksum [256] | e_src [E] | e_w [E]
    //   | h_pos [N*D] | h_neg [N*D]
    char* ws = (char*)d_ws;
    int*   counts   = (int*)ws;                                // becomes offs
    int*   cursor   = (int*)(ws + (size_t)(N + 1) * 4);
    int*   chunksum = (int*)(ws + (size_t)(2 * N + 1) * 4);
    int*   e_src    = (int*)(ws + (size_t)(2 * N + 1 + 256) * 4);
    float* e_w      = (float*)(ws + (size_t)(2 * N + 1 + 256 + E) * 4);
    float* h_pos    = (float*)(ws + (size_t)(2 * N + 1 + 256 + 2 * E) * 4);
    float* h_neg    = h_pos + (size_t)N * D;

    // Zero only the histogram (everything else fully written each call).
    hipMemsetAsync(counts, 0, (size_t)N * 4, stream);

    int eb = (E + 255) / 256;
    hist_kernel<<<eb, 256, 0, stream>>>(dst, counts, E);
    scan_chunk_reduce<<<nchunks, 256, 0, stream>>>(counts, chunksum, N);
    scan_chunksums<<<1, 256, 0, stream>>>(chunksum, nchunks, &counts[N]);
    scan_chunk_apply<<<nchunks, 256, 0, stream>>>(counts, chunksum, cursor, N);
    scatter_kernel<<<eb, 256, 0, stream>>>(w, src, dst, cursor, e_src, e_w, E);

    int nb = (N * 64 + 255) / 256;
    node_agg_kernel<<<nb, 256, 0, stream>>>(feat, counts, e_src, e_w,
                                            h_pos, h_neg, N);

    int gb = (N + 255) / 256;
    out_gemm_kernel<<<gb, 256, 0, stream>>>(feat, h_pos, h_neg, W_fc, b_fc, bias,
                                            coef_self, coef_posi, coef_nega,
                                            (float*)d_out, N);
}

// Round 4
// 202.097 us; speedup vs baseline: 1.6520x; 1.1963x over previous
//
#include <hip/hip_runtime.h>

#define D 64
#define K3 192  // 3*D
#define OUTD 64
#define CHUNK 1024  // elements per scan block (256 thr x 4)

// ---------------------------------------------------------------------------
// Pass 1: histogram of dst -> counts[N]
// ---------------------------------------------------------------------------
__global__ void hist_kernel(const int* __restrict__ dst,
                            int* __restrict__ counts, int E) {
    int i = blockIdx.x * blockDim.x + threadIdx.x;
    if (i < E) atomicAdd(&counts[dst[i]], 1);
}

// ---------------------------------------------------------------------------
// Pass 2a: per-chunk reduce -> chunksum[nchunks]
// ---------------------------------------------------------------------------
__global__ __launch_bounds__(256) void scan_chunk_reduce(
        const int* __restrict__ counts, int* __restrict__ chunksum, int N) {
    int base = blockIdx.x * CHUNK;
    int t = threadIdx.x;
    int idx = base + t * 4;
    int s = 0;
    if (idx + 3 < N) {
        int4 v = *(const int4*)&counts[idx];
        s = v.x + v.y + v.z + v.w;
    } else {
        for (int j = 0; j < 4; ++j)
            if (idx + j < N) s += counts[idx + j];
    }
#pragma unroll
    for (int o = 32; o >= 1; o >>= 1) s += __shfl_xor(s, o);
    __shared__ int wt[4];
    if ((t & 63) == 0) wt[t >> 6] = s;
    __syncthreads();
    if (t == 0) chunksum[blockIdx.x] = wt[0] + wt[1] + wt[2] + wt[3];
}

// ---------------------------------------------------------------------------
// Pass 2b: single-block exclusive scan of chunksums (nchunks <= 256).
// Also writes offs[N] = total (= E).
// ---------------------------------------------------------------------------
__global__ __launch_bounds__(256) void scan_chunksums(
        int* __restrict__ chunksum, int nchunks, int* __restrict__ offsN) {
    __shared__ int sh[256];
    int t = threadIdx.x;
    int v = (t < nchunks) ? chunksum[t] : 0;
    sh[t] = v;
    __syncthreads();
    for (int o = 1; o < 256; o <<= 1) {
        int u = (t >= o) ? sh[t - o] : 0;
        __syncthreads();
        sh[t] += u;
        __syncthreads();
    }
    if (t < nchunks) chunksum[t] = sh[t] - v;   // exclusive
    if (t == nchunks - 1) *offsN = sh[t];       // total = E
}

// ---------------------------------------------------------------------------
// Pass 2c: per-chunk apply: block-local scan + chunk base -> offs, cursor.
// ---------------------------------------------------------------------------
__global__ __launch_bounds__(256) void scan_chunk_apply(
        int* __restrict__ counts,             // in: counts, out: offs
        const int* __restrict__ chunkbase,    // exclusive chunk prefixes
        int* __restrict__ cursor, int N) {
    int base = blockIdx.x * CHUNK;
    int t = threadIdx.x;
    int lane = t & 63;
    int wid = t >> 6;
    int idx = base + t * 4;
    int v[4] = {0, 0, 0, 0};
    if (idx + 3 < N) {
        int4 x = *(const int4*)&counts[idx];
        v[0] = x.x; v[1] = x.y; v[2] = x.z; v[3] = x.w;
    } else {
        for (int j = 0; j < 4; ++j)
            if (idx + j < N) v[j] = counts[idx + j];
    }
    int s = v[0] + v[1] + v[2] + v[3];
    int incl = s;
#pragma unroll
    for (int o = 1; o < 64; o <<= 1) {
        int u = __shfl_up(incl, o);
        if (lane >= o) incl += u;
    }
    __shared__ int wt[4];
    if (lane == 63) wt[wid] = incl;
    __syncthreads();
    int wbase = 0;
    for (int j = 0; j < wid; ++j) wbase += wt[j];
    int run = chunkbase[blockIdx.x] + wbase + (incl - s);
    for (int j = 0; j < 4; ++j) {
        int ij = idx + j;
        if (ij < N) {
            counts[ij] = run;
            cursor[ij] = run;
            run += v[j];
        }
    }
}

// ---------------------------------------------------------------------------
// Pass 3: scatter edges into dst-sorted order; payload packed (w, src).
// ---------------------------------------------------------------------------
__global__ void scatter_kernel(const float* __restrict__ w,
                               const int* __restrict__ src,
                               const int* __restrict__ dst,
                               int* __restrict__ cursor,
                               uint2* __restrict__ e_pack, int E) {
    int i = blockIdx.x * blockDim.x + threadIdx.x;
    if (i >= E) return;
    int d = dst[i];
    int p = atomicAdd(&cursor[d], 1);
    e_pack[p] = make_uint2(__float_as_uint(w[i]), (unsigned)src[i]);
}

// ---------------------------------------------------------------------------
// Pass 4: fused per-node softmax (pos & neg) + aggregation. One wave/node.
// Phase A/B: lane-parallel over edges, shuffle-reduce max/sum.
// Phase C: wave-uniform serial loop; edge metadata via SCALAR loads
//          (readfirstlane'd induction var -> s_load), branchless sign
//          handling via cndmask; unroll 4 for gather MLP. No shuffles.
// ---------------------------------------------------------------------------
__global__ __launch_bounds__(256) void node_agg_kernel(
        const float* __restrict__ feat,
        const int* __restrict__ offs,     // len N+1
        const uint2* __restrict__ e_pack,
        float* __restrict__ h_pos,
        float* __restrict__ h_neg, int N) {
    int lane = threadIdx.x & 63;
    int node = (blockIdx.x * blockDim.x + threadIdx.x) >> 6;
    if (node >= N) return;
    int beg = offs[node];
    int end = offs[node + 1];

    // Phase A: masked maxes
    float mp = -1e30f, mn = -1e30f;
    for (int base = beg; base < end; base += 64) {
        int e = base + lane;
        float we = (e < end) ? __uint_as_float(e_pack[e].x) : 0.0f;
        if (we > 0.0f) mp = fmaxf(mp, we);
        else if (we < 0.0f) mn = fmaxf(mn, -we);
    }
#pragma unroll
    for (int o = 32; o >= 1; o >>= 1) {
        mp = fmaxf(mp, __shfl_xor(mp, o));
        mn = fmaxf(mn, __shfl_xor(mn, o));
    }

    // Phase B: denominators
    float sp = 0.0f, sn = 0.0f;
    for (int base = beg; base < end; base += 64) {
        int e = base + lane;
        float we = (e < end) ? __uint_as_float(e_pack[e].x) : 0.0f;
        if (we > 0.0f) sp += __expf(we - mp);
        else if (we < 0.0f) sn += __expf(-we - mn);
    }
#pragma unroll
    for (int o = 32; o >= 1; o >>= 1) {
        sp += __shfl_xor(sp, o);
        sn += __shfl_xor(sn, o);
    }
    float rp = 1.0f / (sp + 1e-16f);
    float rn = 1.0f / (sn + 1e-16f);

    // Phase C: aggregation, wave-uniform scalar metadata loop
    float accp = 0.0f, accn = 0.0f;
    int ubeg = __builtin_amdgcn_readfirstlane(beg);
    int uend = __builtin_amdgcn_readfirstlane(end);
#pragma unroll 4
    for (int e = ubeg; e < uend; ++e) {
        uint2 pk = e_pack[e];               // wave-uniform -> s_load
        float wj = __uint_as_float(pk.x);
        int   sj = (int)pk.y;
        bool pos = wj > 0.0f;
        float m = pos ? mp : mn;
        float r = pos ? rp : rn;
        float aj = __expf(fabsf(wj) - m) * r;
        aj = (wj == 0.0f) ? 0.0f : aj;      // kill w==0 (and its inf path)
        float t = feat[(size_t)sj * D + lane] * aj;
        accp += pos ? t : 0.0f;
        accn += pos ? 0.0f : t;
    }
    h_pos[(size_t)node * D + lane] = accp;
    h_neg[(size_t)node * D + lane] = accn;
}

// ---------------------------------------------------------------------------
// Pass 5: output projection.
// ---------------------------------------------------------------------------
__global__ __launch_bounds__(256) void out_gemm_kernel(
        const float* __restrict__ feat,
        const float* __restrict__ h_pos,
        const float* __restrict__ h_neg,
        const float* __restrict__ W_fc,
        const float* __restrict__ b_fc,
        const float* __restrict__ bias,
        const float* __restrict__ coef_self,
        const float* __restrict__ coef_posi,
        const float* __restrict__ coef_nega,
        float* __restrict__ out,
        int N) {
    __shared__ float Wt[K3 * OUTD];  // Wt[k][o] = W_fc[o][k]
    for (int i = threadIdx.x; i < K3 * OUTD; i += blockDim.x) {
        int k = i >> 6;
        int o = i & 63;
        Wt[i] = W_fc[o * K3 + k];
    }
    __syncthreads();

    int n = blockIdx.x * blockDim.x + threadIdx.x;
    if (n >= N) return;

    float cf[3];
    cf[0] = coef_self[0];
    cf[1] = coef_posi[0];
    cf[2] = coef_nega[0];
    const float* segs[3];
    segs[0] = feat;
    segs[1] = h_pos;
    segs[2] = h_neg;

    float acc[OUTD];
#pragma unroll
    for (int o = 0; o < OUTD; ++o) acc[o] = b_fc[o] + bias[o];

    for (int sg = 0; sg < 3; ++sg) {
        const float4* p = (const float4*)(segs[sg] + (size_t)n * D);
        float c = cf[sg];
        for (int kk = 0; kk < D / 4; ++kk) {
            float4 v4 = p[kk];
            float cv[4];
            cv[0] = v4.x * c; cv[1] = v4.y * c; cv[2] = v4.z * c; cv[3] = v4.w * c;
#pragma unroll
            for (int j = 0; j < 4; ++j) {
                const float* wrow = &Wt[((sg * (D / 4) + kk) * 4 + j) * OUTD];
#pragma unroll
                for (int o = 0; o < OUTD; o += 4) {
                    float4 wv = *(const float4*)&wrow[o];
                    acc[o + 0] += cv[j] * wv.x;
                    acc[o + 1] += cv[j] * wv.y;
                    acc[o + 2] += cv[j] * wv.z;
                    acc[o + 3] += cv[j] * wv.w;
                }
            }
        }
    }

    float* op = out + (size_t)n * OUTD;
#pragma unroll
    for (int o = 0; o < OUTD; o += 4) {
        float4 r;
        r.x = acc[o + 0]; r.y = acc[o + 1]; r.z = acc[o + 2]; r.w = acc[o + 3];
        *(float4*)&op[o] = r;
    }
}

extern "C" void kernel_launch(void* const* d_in, const int* in_sizes, int n_in,
                              void* d_out, int out_size, void* d_ws, size_t ws_size,
                              hipStream_t stream) {
    const float* feat      = (const float*)d_in[0];
    const float* w         = (const float*)d_in[1];
    const float* W_fc      = (const float*)d_in[2];
    const float* b_fc      = (const float*)d_in[3];
    const float* bias      = (const float*)d_in[4];
    const float* coef_self = (const float*)d_in[5];
    const float* coef_posi = (const float*)d_in[6];
    const float* coef_nega = (const float*)d_in[7];
    const int*   src       = (const int*)d_in[8];
    const int*   dst       = (const int*)d_in[9];

    const int E = in_sizes[1];
    const int N = in_sizes[0] / D;
    const int nchunks = (N + CHUNK - 1) / CHUNK;  // 49 for N=50000 (<=256 req.)

    // Workspace layout (4B elems, e_pack 8B-aligned):
    //   counts/offs [N+1] | cursor [N] | chunksum [256] | pad | e_pack [E]x8B
    //   | h_pos [N*D] | h_neg [N*D]
    char* ws = (char*)d_ws;
    int*   counts   = (int*)ws;                                // becomes offs
    int*   cursor   = (int*)(ws + (size_t)(N + 1) * 4);
    int*   chunksum = (int*)(ws + (size_t)(2 * N + 1) * 4);
    size_t epack_off = (((size_t)(2 * N + 1 + 256) * 4) + 7) & ~(size_t)7;
    uint2* e_pack   = (uint2*)(ws + epack_off);
    float* h_pos    = (float*)(ws + epack_off + (size_t)E * 8);
    float* h_neg    = h_pos + (size_t)N * D;

    // Zero only the histogram (everything else fully written each call).
    hipMemsetAsync(counts, 0, (size_t)N * 4, stream);

    int eb = (E + 255) / 256;
    hist_kernel<<<eb, 256, 0, stream>>>(dst, counts, E);
    scan_chunk_reduce<<<nchunks, 256, 0, stream>>>(counts, chunksum, N);
    scan_chunksums<<<1, 256, 0, stream>>>(chunksum, nchunks, &counts[N]);
    scan_chunk_apply<<<nchunks, 256, 0, stream>>>(counts, chunksum, cursor, N);
    scatter_kernel<<<eb, 256, 0, stream>>>(w, src, dst, cursor, e_pack, E);

    int nb = (N * 64 + 255) / 256;
    node_agg_kernel<<<nb, 256, 0, stream>>>(feat, counts, e_pack, h_pos, h_neg, N);

    int gb = (N + 255) / 256;
    out_gemm_kernel<<<gb, 256, 0, stream>>>(feat, h_pos, h_neg, W_fc, b_fc, bias,
                                            coef_self, coef_posi, coef_nega,
                                            (float*)d_out, N);
}